// Round 6
// baseline (27.133 us; speedup 1.0000x reference)
//
#include <hip/hip_runtime.h>
#include <math.h>

#define NB 512
#define HW 169
#define NA 5
#define NCH 125
#define BLOCK 256
#define NBLOCKS ((NB * HW) / BLOCK)   // 338
#define REC 8                          // padded per-block record (dwords)

__device__ __forceinline__ float u2f_(unsigned int u) { return __uint_as_float(u); }
__device__ __forceinline__ unsigned int f2u_(float f) { return __float_as_uint(f); }

__global__ __launch_bounds__(BLOCK, 2) void yolo_loss_fused(
    const float* __restrict__ P,    // [B][125][169] (channel-major)
    const float* __restrict__ T,    // [B][169][125]
    const float* __restrict__ ANC,  // [5][2]
    unsigned int* __restrict__ wsrec,  // [NBLOCKS][REC] records (bit-cast f32 + mask)
    unsigned int* __restrict__ counter,// 1 int, memset to 0 before this kernel
    float* __restrict__ out)
{
    int t = threadIdx.x;
    int idx = blockIdx.x * BLOCK + t;
    int b  = idx / HW;
    int hw = idx - b * HW;

    const float* Pb = P + (size_t)b * NCH * HW + hw;
    const float* Tb = T + ((size_t)b * HW + hw) * NCH;

    // ---- issue all 45 independent loads first
    float gx[NA], gy[NA], gw_[NA], gh[NA], gc[NA];
    float rx[NA], ry[NA], rw[NA], rh[NA];
#pragma unroll
    for (int a = 0; a < NA; ++a) {
        int c0 = a * 25;
        gc[a]  = Tb[c0 + 20];
        gx[a]  = Tb[c0 + 21];
        gy[a]  = Tb[c0 + 22];
        gw_[a] = Tb[c0 + 23];
        gh[a]  = Tb[c0 + 24];
    }
#pragma unroll
    for (int a = 0; a < NA; ++a) {
        int c0 = a * 25;
        rx[a] = Pb[(c0 + 21) * HW];
        ry[a] = Pb[(c0 + 22) * HW];
        rw[a] = Pb[(c0 + 23) * HW];
        rh[a] = Pb[(c0 + 24) * HW];
    }

    // ---- transforms + per-(cell,anchor) work
    float px[NA], py[NA], pw[NA], ph[NA];
#pragma unroll
    for (int a = 0; a < NA; ++a) {
        px[a] = 1.0f / (1.0f + expf(-rx[a]));
        py[a] = 1.0f / (1.0f + expf(-ry[a]));
        pw[a] = expf(rw[a]);
        ph[a] = expf(rh[a]);
    }

    float contrib[NA];
    int cmask = 0;
#pragma unroll
    for (int i = 0; i < NA; ++i) {
        float aw = ANC[2 * i], ah = ANC[2 * i + 1];
        float ax1 = px[i] - aw * 0.5f, ax2 = px[i] + aw * 0.5f;
        float ay1 = py[i] - ah * 0.5f, ay2 = py[i] + ah * 0.5f;
        float area_a = (ax2 - ax1) * (ay2 - ay1);
        float best = -1.0f; int bestj = 0;
#pragma unroll
        for (int j = 0; j < NA; ++j) {
            float bx1 = gx[j] - gw_[j] * 0.5f, bx2 = gx[j] + gw_[j] * 0.5f;
            float by1 = gy[j] - gh[j] * 0.5f, by2 = gy[j] + gh[j] * 0.5f;
            float iw = fmaxf(fminf(ax2, bx2) - fmaxf(ax1, bx1), 0.0f);
            float ih = fmaxf(fminf(ay2, by2) - fmaxf(ay1, by1), 0.0f);
            float inter = iw * ih;
            float area_b = (bx2 - bx1) * (by2 - by1);
            float iou = inter / (area_a + area_b - inter + 1e-10f);
            if (iou > best) { best = iou; bestj = j; }   // strict > == jnp.argmax first-max
        }
        cmask |= (1 << bestj);
        float dx = px[i] - gx[i], dy = py[i] - gy[i];
        float dw = pw[i] - gw_[i], dh = ph[i] - gh[i];
        contrib[i] = gc[i] * gc[i] * (dx * dx + dy * dy + dw * dw + dh * dh);
    }

    // ---- wave shuffle reduce -> cross-wave via LDS
    __shared__ float sred[4][NA];
    __shared__ int smask[4];
    __shared__ int swin;
    int lane = t & 63, wid = t >> 6;

#pragma unroll
    for (int i = 0; i < NA; ++i) {
        float v = contrib[i];
        for (int off = 32; off; off >>= 1) v += __shfl_down(v, off, 64);
        if (lane == 0) sred[wid][i] = v;
    }
    for (int off = 32; off; off >>= 1) cmask |= __shfl_down(cmask, off, 64);
    if (lane == 0) smask[wid] = cmask;
    __syncthreads();

    // ---- publish record (agent-scope), then acq_rel arrival; last block finalizes
    if (t == 0) {
        int m = smask[0] | smask[1] | smask[2] | smask[3];
        unsigned int* r = wsrec + blockIdx.x * REC;
#pragma unroll
        for (int i = 0; i < NA; ++i) {
            float s = sred[0][i] + sred[1][i] + sred[2][i] + sred[3][i];
            __hip_atomic_store(&r[i], f2u_(s), __ATOMIC_RELAXED, __HIP_MEMORY_SCOPE_AGENT);
        }
        __hip_atomic_store(&r[5], (unsigned int)m, __ATOMIC_RELAXED, __HIP_MEMORY_SCOPE_AGENT);
        unsigned int old = __hip_atomic_fetch_add(counter, 1u, __ATOMIC_ACQ_REL,
                                                  __HIP_MEMORY_SCOPE_AGENT);
        swin = (old == NBLOCKS - 1);
    }
    __syncthreads();

    if (swin && t < 64) {
        double s[NA] = {0, 0, 0, 0, 0};
        int m = 0;
        for (int e = t; e < NBLOCKS; e += 64) {
            const unsigned int* r = wsrec + e * REC;
            unsigned int w0 = __hip_atomic_load(&r[0], __ATOMIC_RELAXED, __HIP_MEMORY_SCOPE_AGENT);
            unsigned int w1 = __hip_atomic_load(&r[1], __ATOMIC_RELAXED, __HIP_MEMORY_SCOPE_AGENT);
            unsigned int w2 = __hip_atomic_load(&r[2], __ATOMIC_RELAXED, __HIP_MEMORY_SCOPE_AGENT);
            unsigned int w3 = __hip_atomic_load(&r[3], __ATOMIC_RELAXED, __HIP_MEMORY_SCOPE_AGENT);
            unsigned int w4 = __hip_atomic_load(&r[4], __ATOMIC_RELAXED, __HIP_MEMORY_SCOPE_AGENT);
            unsigned int w5 = __hip_atomic_load(&r[5], __ATOMIC_RELAXED, __HIP_MEMORY_SCOPE_AGENT);
            s[0] += (double)u2f_(w0); s[1] += (double)u2f_(w1);
            s[2] += (double)u2f_(w2); s[3] += (double)u2f_(w3);
            s[4] += (double)u2f_(w4);
            m |= (int)w5;
        }
#pragma unroll
        for (int i = 0; i < NA; ++i)
            for (int off = 32; off; off >>= 1) s[i] += __shfl_down(s[i], off, 64);
        for (int off = 32; off; off >>= 1) m |= __shfl_down(m, off, 64);

        if (t == 0) {
            double tot = 0.0;
#pragma unroll
            for (int i = 0; i < NA; ++i)
                if ((m >> i) & 1) tot += s[i];
            out[0] = (float)((5.0 / 512.0) * tot);
        }
    }
}

extern "C" void kernel_launch(void* const* d_in, const int* in_sizes, int n_in,
                              void* d_out, int out_size, void* d_ws, size_t ws_size,
                              hipStream_t stream) {
    const float* P   = (const float*)d_in[0];
    const float* T   = (const float*)d_in[1];
    const float* ANC = (const float*)d_in[2];
    float* out = (float*)d_out;

    unsigned int* wsrec  = (unsigned int*)d_ws;          // NBLOCKS * REC words
    unsigned int* counter = wsrec + NBLOCKS * REC;       // 1 word

    hipMemsetAsync(counter, 0, sizeof(unsigned int), stream);
    yolo_loss_fused<<<NBLOCKS, BLOCK, 0, stream>>>(P, T, ANC, wsrec, counter, out);
}

// Round 7
// 21.668 us; speedup vs baseline: 1.2523x; 1.2523x over previous
//
#include <hip/hip_runtime.h>
#include <math.h>

#define NB 512
#define HW 169
#define NA 5
#define NCH 125
#define BLOCK 64                        // one wave per block
#define NBLOCKS ((NB * HW) / BLOCK)     // 1352 exactly
#define REC 8                           // padded per-block record (dwords)

__global__ __launch_bounds__(BLOCK, 2) void yolo_loss_main(
    const float* __restrict__ P,    // [B][125][169] (channel-major)
    const float* __restrict__ T,    // [B][169][125]
    const float* __restrict__ ANC,  // [5][2]
    float* __restrict__ brec)       // [NBLOCKS][REC]
{
    __shared__ float sT[BLOCK * 25];    // 6.4 KB: [cell_local][slot], slot = a*5 + {conf,x,y,w,h}

    int t = threadIdx.x;                // lane 0..63
    int cell0 = blockIdx.x * BLOCK;

    // ---- phase 1a: cooperative COALESCED T gather of the needed-float set.
    // needed-float n = cell_local*25 + slot; consecutive n -> near-consecutive addrs
    // (5-float chunks every 100 B) -> ~20 merged lines/instr instead of 64.
    float tv[25];
#pragma unroll
    for (int r = 0; r < 25; ++r) {
        int n  = r * 64 + t;
        int cl = n / 25;                // local cell
        int s  = n - cl * 25;           // slot 0..24
        int a  = s / 5;
        int k  = s - a * 5;
        tv[r] = T[(size_t)(cell0 + cl) * NCH + a * 25 + 20 + k];
    }

    // ---- phase 1b: P loads (already coalesced: lanes consecutive in 676-B planes)
    int idx = cell0 + t;
    int b  = idx / HW;
    int hw = idx - b * HW;
    const float* Pb = P + (size_t)b * NCH * HW + hw;
    float rx[NA], ry[NA], rw[NA], rh[NA];
#pragma unroll
    for (int a = 0; a < NA; ++a) {
        int c0 = a * 25;
        rx[a] = Pb[(c0 + 21) * HW];
        ry[a] = Pb[(c0 + 22) * HW];
        rw[a] = Pb[(c0 + 23) * HW];
        rh[a] = Pb[(c0 + 24) * HW];
    }

    // ---- phase 2: LDS redistribute (write addr = n: linear, conflict-free)
#pragma unroll
    for (int r = 0; r < 25; ++r)
        sT[r * 64 + t] = tv[r];
    __syncthreads();                    // 1 wave: compiles to waitcnt + cheap barrier

    // read own cell: stride 25 across lanes, coprime with 32 banks -> conflict-free
    float gx[NA], gy[NA], gw_[NA], gh[NA], gc[NA];
#pragma unroll
    for (int a = 0; a < NA; ++a) {
        gc[a]  = sT[t * 25 + a * 5 + 0];
        gx[a]  = sT[t * 25 + a * 5 + 1];
        gy[a]  = sT[t * 25 + a * 5 + 2];
        gw_[a] = sT[t * 25 + a * 5 + 3];
        gh[a]  = sT[t * 25 + a * 5 + 4];
    }

    // ---- phase 3: transforms + IoU/argmax + masked SSE contribution
    float px[NA], py[NA], pw[NA], ph[NA];
#pragma unroll
    for (int a = 0; a < NA; ++a) {
        px[a] = 1.0f / (1.0f + expf(-rx[a]));
        py[a] = 1.0f / (1.0f + expf(-ry[a]));
        pw[a] = expf(rw[a]);
        ph[a] = expf(rh[a]);
    }

    float contrib[NA];
    int cmask = 0;
#pragma unroll
    for (int i = 0; i < NA; ++i) {
        float aw = ANC[2 * i], ah = ANC[2 * i + 1];
        float ax1 = px[i] - aw * 0.5f, ax2 = px[i] + aw * 0.5f;
        float ay1 = py[i] - ah * 0.5f, ay2 = py[i] + ah * 0.5f;
        float area_a = (ax2 - ax1) * (ay2 - ay1);
        float best = -1.0f; int bestj = 0;
#pragma unroll
        for (int j = 0; j < NA; ++j) {
            float bx1 = gx[j] - gw_[j] * 0.5f, bx2 = gx[j] + gw_[j] * 0.5f;
            float by1 = gy[j] - gh[j] * 0.5f, by2 = gy[j] + gh[j] * 0.5f;
            float iw = fmaxf(fminf(ax2, bx2) - fmaxf(ax1, bx1), 0.0f);
            float ih = fmaxf(fminf(ay2, by2) - fmaxf(ay1, by1), 0.0f);
            float inter = iw * ih;
            float area_b = (bx2 - bx1) * (by2 - by1);
            float iou = inter / (area_a + area_b - inter + 1e-10f);
            if (iou > best) { best = iou; bestj = j; }   // strict > == jnp.argmax first-max
        }
        cmask |= (1 << bestj);
        float dx = px[i] - gx[i], dy = py[i] - gy[i];
        float dw = pw[i] - gw_[i], dh = ph[i] - gh[i];
        contrib[i] = gc[i] * gc[i] * (dx * dx + dy * dy + dw * dw + dh * dh);
    }

    // ---- phase 4: single-wave shuffle reduce -> one 32-B record
#pragma unroll
    for (int i = 0; i < NA; ++i)
        for (int off = 32; off; off >>= 1) contrib[i] += __shfl_down(contrib[i], off, 64);
    for (int off = 32; off; off >>= 1) cmask |= __shfl_down(cmask, off, 64);

    if (t == 0) {
        float4* r4 = (float4*)(brec + blockIdx.x * REC);
        r4[0] = make_float4(contrib[0], contrib[1], contrib[2], contrib[3]);
        r4[1] = make_float4(contrib[4], __int_as_float(cmask), 0.0f, 0.0f);
    }
}

__global__ __launch_bounds__(256) void yolo_loss_final(
    const float* __restrict__ brec, float* __restrict__ out)
{
    __shared__ double sred[4][NA];
    __shared__ int smask[4];
    int t = threadIdx.x, lane = t & 63, wid = t >> 6;
    const float4* r4 = (const float4*)brec;

    double s[NA] = {0, 0, 0, 0, 0};
    int m = 0;
    for (int e = t; e < NBLOCKS; e += 256) {
        float4 lo = r4[e * 2];
        float4 hi = r4[e * 2 + 1];
        s[0] += (double)lo.x; s[1] += (double)lo.y;
        s[2] += (double)lo.z; s[3] += (double)lo.w;
        s[4] += (double)hi.x;
        m |= __float_as_int(hi.y);
    }
#pragma unroll
    for (int i = 0; i < NA; ++i)
        for (int off = 32; off; off >>= 1) s[i] += __shfl_down(s[i], off, 64);
    for (int off = 32; off; off >>= 1) m |= __shfl_down(m, off, 64);
    if (lane == 0) {
#pragma unroll
        for (int i = 0; i < NA; ++i) sred[wid][i] = s[i];
        smask[wid] = m;
    }
    __syncthreads();

    if (t == 0) {
        int mm = smask[0] | smask[1] | smask[2] | smask[3];
        double tot = 0.0;
#pragma unroll
        for (int i = 0; i < NA; ++i)
            if ((mm >> i) & 1)
                tot += sred[0][i] + sred[1][i] + sred[2][i] + sred[3][i];
        out[0] = (float)((5.0 / 512.0) * tot);
    }
}

extern "C" void kernel_launch(void* const* d_in, const int* in_sizes, int n_in,
                              void* d_out, int out_size, void* d_ws, size_t ws_size,
                              hipStream_t stream) {
    const float* P   = (const float*)d_in[0];
    const float* T   = (const float*)d_in[1];
    const float* ANC = (const float*)d_in[2];
    float* out = (float*)d_out;

    float* brec = (float*)d_ws;   // NBLOCKS * REC floats

    yolo_loss_main<<<NBLOCKS, BLOCK, 0, stream>>>(P, T, ANC, brec);
    yolo_loss_final<<<1, 256, 0, stream>>>(brec, out);
}